// Round 7
// baseline (295.786 us; speedup 1.0000x reference)
//
#include <hip/hip_runtime.h>
#include <hip/hip_bf16.h>
#include <cstdint>
#include <cstddef>

#define EMB   2048
#define NH_   32
#define NG_   8
#define DH_   64
#define SEQ_  2048
#define BB_   2
#define MTOT  4096
#define LDQKV 3072

typedef __attribute__((ext_vector_type(8))) short s16x8;
typedef __attribute__((ext_vector_type(8))) unsigned short u16x8;
typedef __attribute__((ext_vector_type(4))) float f32x4;
typedef __attribute__((ext_vector_type(16))) float f32x16;
typedef __attribute__((ext_vector_type(4))) unsigned int u32x4;
typedef __attribute__((ext_vector_type(2))) unsigned int u32x2;
typedef __attribute__((ext_vector_type(2))) int i32x2;

__device__ __forceinline__ float bf2f(unsigned short u) {
  unsigned int x = (unsigned int)u << 16; return __uint_as_float(x);
}
__device__ __forceinline__ unsigned short f2bf(float f) {
  unsigned int x = __float_as_uint(f);
  x = x + 0x7FFFu + ((x >> 16) & 1u);          // RNE
  return (unsigned short)(x >> 16);
}
__device__ __forceinline__ float ninf() { return __int_as_float(0xff800000); }
__device__ __forceinline__ unsigned int pack_bf2(float a, float b) {
  unsigned int r;
  asm("v_cvt_pk_bf16_f32 %0, %1, %2" : "=v"(r) : "v"(a), "v"(b));
  return r;
}
// lane i (<32): a.lo stays, a.hi <- b.lo ; b.lo <- a.hi, b.hi stays (32-lane half swap)
__device__ __forceinline__ void plswap(unsigned int& a, unsigned int& b) {
  i32x2 r = __builtin_amdgcn_permlane32_swap((int)a, (int)b, false, false);
  a = (unsigned int)r[0]; b = (unsigned int)r[1];
}
__device__ __forceinline__ void plswapf(float& a, float& b) {
  unsigned int ua = __float_as_uint(a), ub = __float_as_uint(b);
  plswap(ua, ub);
  a = __uint_as_float(ua); b = __uint_as_float(ub);
}

__device__ __forceinline__ void glds16(const void* g, void* l) {
  __builtin_amdgcn_global_load_lds((const __attribute__((address_space(1))) void*)g,
                                   (__attribute__((address_space(3))) void*)l, 16, 0, 0);
}

// ---------- x f32 -> bf16 ----------
__global__ __launch_bounds__(256)
void cvtx(const float* __restrict__ x, unsigned short* __restrict__ xb) {
  size_t i = (size_t)blockIdx.x * 256 + threadIdx.x;
  float4 a = *(const float4*)(x + i * 8);
  float4 c = *(const float4*)(x + i * 8 + 4);
  u16x8 o;
  o[0] = f2bf(a.x); o[1] = f2bf(a.y); o[2] = f2bf(a.z); o[3] = f2bf(a.w);
  o[4] = f2bf(c.x); o[5] = f2bf(c.y); o[6] = f2bf(c.z); o[7] = f2bf(c.w);
  *(u16x8*)(xb + i * 8) = o;
}

// ---------- W[K=2048][N] f32 -> Wt[N][2048] bf16 ----------
__global__ __launch_bounds__(256)
void wtrans(const float* __restrict__ in, unsigned short* __restrict__ out, int N) {
  __shared__ float tile[64][65];
  const int tid = threadIdx.x;
  const int n0 = blockIdx.x * 64, k0 = blockIdx.y * 64;
  #pragma unroll
  for (int jj = 0; jj < 4; ++jj) {
    int r = (tid >> 4) + jj * 16;
    int c = (tid & 15) * 4;
    float4 v = *(const float4*)(in + (size_t)(k0 + r) * N + n0 + c);
    tile[r][c] = v.x; tile[r][c + 1] = v.y; tile[r][c + 2] = v.z; tile[r][c + 3] = v.w;
  }
  __syncthreads();
  #pragma unroll
  for (int rep = 0; rep < 2; ++rep) {
    int u = rep * 256 + tid;
    int nl = u >> 3, ch = u & 7;
    u16x8 o;
    #pragma unroll
    for (int e = 0; e < 8; ++e) o[e] = f2bf(tile[ch * 8 + e][nl]);
    *(u16x8*)(out + (size_t)(n0 + nl) * 2048 + k0 + ch * 8) = o;
  }
}

// ---------- MFMA GEMM: C[M,N] = A[M,2048] @ Bt[N,2048]^T ; BM=BN=128, BK=32 ----------
template<int BF16OUT>
__global__ __launch_bounds__(256)
void gemm_bt(const unsigned short* __restrict__ A, const unsigned short* __restrict__ Bt,
             void* __restrict__ C, int ldc) {
  __shared__ __align__(16) unsigned short As[128 * 32];
  __shared__ __align__(16) unsigned short Bs[128 * 32];
  const int tid = threadIdx.x;
  const int w = tid >> 6, lane = tid & 63;
  const int grp = lane >> 4, l15 = lane & 15;
  const int wr = w >> 1, wc = w & 1;
  const int bm = blockIdx.y * 128, bn = blockIdx.x * 128;
  f32x4 acc[4][4] = {};
  for (int k0 = 0; k0 < 2048; k0 += 32) {
    #pragma unroll
    for (int j = 0; j < 2; ++j) {
      int unit = (j * 4 + w) * 64 + lane;
      int row = unit >> 2, ch = unit & 3;
      glds16(A  + (size_t)(bm + row) * 2048 + k0 + ch * 8, (char*)As + (j * 4 + w) * 1024);
      glds16(Bt + (size_t)(bn + row) * 2048 + k0 + ch * 8, (char*)Bs + (j * 4 + w) * 1024);
    }
    __syncthreads();
    s16x8 af[4], bf[4];
    #pragma unroll
    for (int i = 0; i < 4; ++i)
      af[i] = *(const s16x8*)((const char*)As + (wr * 64 + i * 16 + l15) * 64 + grp * 16);
    #pragma unroll
    for (int j = 0; j < 4; ++j)
      bf[j] = *(const s16x8*)((const char*)Bs + (wc * 64 + j * 16 + l15) * 64 + grp * 16);
    #pragma unroll
    for (int i = 0; i < 4; ++i)
      #pragma unroll
      for (int j = 0; j < 4; ++j)
        acc[i][j] = __builtin_amdgcn_mfma_f32_16x16x32_bf16(af[i], bf[j], acc[i][j], 0, 0, 0);
    __syncthreads();
  }
  #pragma unroll
  for (int i = 0; i < 4; ++i)
    #pragma unroll
    for (int j = 0; j < 4; ++j)
      #pragma unroll
      for (int r = 0; r < 4; ++r) {
        int row = bm + wr * 64 + i * 16 + grp * 4 + r;
        int col = bn + wc * 64 + j * 16 + l15;
        float v = acc[i][j][r];
        if (BF16OUT) ((unsigned short*)C)[(size_t)row * ldc + col] = f2bf(v);
        else         ((float*)C)[(size_t)row * ldc + col] = v;
      }
}

// ---------- fused RMSNorm(D=64) + RoPE, in-place bf16; optional post-scale ----------
__global__ __launch_bounds__(256)
void rmsrope(unsigned short* __restrict__ t, const float* __restrict__ scale,
             const float* __restrict__ cs, const float* __restrict__ sn, int coff, float post) {
  int m = blockIdx.x * 4 + (threadIdx.x >> 6);
  int h = blockIdx.y;
  int lane = threadIdx.x & 63;
  int spos = m & (SEQ_ - 1);
  unsigned short* p = t + (size_t)m * LDQKV + coff + h * 64 + lane;
  float val = bf2f(*p);
  float sq = val * val;
  #pragma unroll
  for (int off = 32; off; off >>= 1) sq += __shfl_xor(sq, off);
  float r = rsqrtf(sq * (1.f / 64.f) + 1e-6f);
  float xn = val * r * scale[lane];
  float partner = __shfl_xor(xn, 32);
  float c = cs[spos * 64 + lane], s = sn[spos * 64 + lane];
  float o = (lane < 32) ? (xn * c - partner * s) : fmaf(xn, c, partner * s);
  *p = f2bf(o * post);
}

// ---------- v region of qkv -> vT[(b*8+g)*64 + d][s] bf16 ----------
__global__ __launch_bounds__(256)
void vtrans(const unsigned short* __restrict__ qkv, unsigned short* __restrict__ vT) {
  __shared__ unsigned short tile[64][72];
  const int tid = threadIdx.x;
  const int st = blockIdx.x;
  const int bg = blockIdx.y;
  const int b = bg >> 3, g = bg & 7;
  #pragma unroll
  for (int rep = 0; rep < 2; ++rep) {
    int u = rep * 256 + tid;
    int sl = u >> 3, ch = u & 7;
    u16x8 v = *(const u16x8*)(qkv + (size_t)(b * SEQ_ + st * 64 + sl) * LDQKV + 2560 + g * 64 + ch * 8);
    #pragma unroll
    for (int e = 0; e < 8; ++e) tile[sl][ch * 8 + e] = v[e];
  }
  __syncthreads();
  #pragma unroll
  for (int rep = 0; rep < 2; ++rep) {
    int u = rep * 256 + tid;
    int d = u >> 3, ch = u & 7;
    u16x8 o;
    #pragma unroll
    for (int e = 0; e < 8; ++e) o[e] = tile[ch * 8 + e][d];
    *(u16x8*)(vT + (size_t)(bg * 64 + d) * SEQ_ + st * 64 + ch * 8) = o;
  }
}

// ---------- MFMA flash attention v4: no-max softmax, 1 wave per q-tile ----------
// Logits are bounded: RMSNorm => |q|=|k|=8, |s|<=8, exp2-domain |st|<=11.54 —
// fixed-shift softmax is exact (no overflow), so no running max, no rescale.
// One wave owns one 32-row q-tile; 64-thread blocks (no LDS/barriers), grid
// ordered longest-tile-first for LPT packing. S^T = mfma32(K,Q): col=l31=q, so
// l/linv are lane-local with the O^T accumulator; P redistribution via
// permlane32_swap. Q pre-scaled by 0.125*log2e -> exp2 directly.
__global__ __launch_bounds__(64)
void attn_mfma4(const unsigned short* __restrict__ qkv, const unsigned short* __restrict__ vT,
                unsigned short* __restrict__ ctx) {
  const int lane = threadIdx.x;
  const int l31 = lane & 31, half = lane >> 5;
  const int bid = blockIdx.x;
  const int qt = 63 - (bid >> 6);               // longest first
  const int bh = bid & 63;
  const int b = bh >> 5, h = bh & 31, g = h >> 2;
  const int qbase = qt * 32;
  const int nkt = qt + 1;

  const unsigned short* qp = qkv + (size_t)(b * SEQ_ + l31) * LDQKV + h * 64 + half * 8;
  const unsigned short* kp = qkv + (size_t)(b * SEQ_ + l31) * LDQKV + 2048 + g * 64 + half * 8;
  const unsigned short* vp = vT + (size_t)((b * NG_ + g) * 64 + l31) * SEQ_ + half * 8;

  s16x8 qf[4];
  #pragma unroll
  for (int s = 0; s < 4; ++s)
    qf[s] = *(const s16x8*)(qp + (size_t)qbase * LDQKV + s * 16);

  f32x16 acc0 = {}, acc1 = {};
  float l_st = 0.f;

  auto loadk = [&](s16x8 (&KF)[4], int kb) {
    #pragma unroll
    for (int s = 0; s < 4; ++s)
      KF[s] = *(const s16x8*)(kp + (size_t)kb * LDQKV + s * 16);
  };

  auto body = [&](const s16x8 (&KF)[4], int kt_) {
    const int kbase = kt_ * 32;
    s16x8 vf00 = *(const s16x8*)(vp + kbase);
    s16x8 vf01 = *(const s16x8*)(vp + kbase + 16);
    s16x8 vf10 = *(const s16x8*)(vp + (size_t)32 * SEQ_ + kbase);
    s16x8 vf11 = *(const s16x8*)(vp + (size_t)32 * SEQ_ + kbase + 16);
    f32x16 st = {};
    #pragma unroll
    for (int s = 0; s < 4; ++s)
      st = __builtin_amdgcn_mfma_f32_32x32x16_bf16(KF[s], qf[s], st, 0, 0, 0);
    if (kt_ == qt) {                           // mask key > q (kbase == qbase)
      #pragma unroll
      for (int r = 0; r < 16; ++r) {
        int key = (r & 3) + 8 * (r >> 2) + 4 * half;
        if (key > l31) st[r] = ninf();
      }
    }
    float p[16];
    #pragma unroll
    for (int r = 0; r < 16; ++r) p[r] = exp2f(st[r]);   // exp2(-inf)=0 handles mask
    float s8[8];
    #pragma unroll
    for (int r = 0; r < 8; ++r) s8[r] = p[r] + p[r + 8];
    float s4a = s8[0] + s8[1], s4b = s8[2] + s8[3];
    float s4c = s8[4] + s8[5], s4d = s8[6] + s8[7];
    float psum = (s4a + s4b) + (s4c + s4d);
    { float a = psum, bsw = psum; plswapf(a, bsw); psum = a + bsw; }
    l_st += psum;
    unsigned int PK[8];
    #pragma unroll
    for (int j = 0; j < 8; ++j) PK[j] = pack_bf2(p[2 * j], p[2 * j + 1]);
    plswap(PK[0], PK[2]); plswap(PK[1], PK[3]);
    plswap(PK[4], PK[6]); plswap(PK[5], PK[7]);
    u32x4 pb0u, pb1u;
    pb0u[0] = PK[0]; pb0u[1] = PK[1]; pb0u[2] = PK[2]; pb0u[3] = PK[3];
    pb1u[0] = PK[4]; pb1u[1] = PK[5]; pb1u[2] = PK[6]; pb1u[3] = PK[7];
    s16x8 pb0 = __builtin_bit_cast(s16x8, pb0u);
    s16x8 pb1 = __builtin_bit_cast(s16x8, pb1u);
    acc0 = __builtin_amdgcn_mfma_f32_32x32x16_bf16(vf00, pb0, acc0, 0, 0, 0);
    acc0 = __builtin_amdgcn_mfma_f32_32x32x16_bf16(vf01, pb1, acc0, 0, 0, 0);
    acc1 = __builtin_amdgcn_mfma_f32_32x32x16_bf16(vf10, pb0, acc1, 0, 0, 0);
    acc1 = __builtin_amdgcn_mfma_f32_32x32x16_bf16(vf11, pb1, acc1, 0, 0, 0);
  };

  s16x8 kA[4], kB[4];
  loadk(kA, 0);
  for (int kt = 0; kt < nkt; kt += 2) {
    loadk(kB, (kt + 1 < nkt) ? (kt + 1) * 32 : kt * 32);
    body(kA, kt);
    if (kt + 1 >= nkt) break;
    loadk(kA, (kt + 2 < nkt) ? (kt + 2) * 32 : (kt + 1) * 32);
    body(kB, kt + 1);
  }

  const float linv = 1.f / l_st;
  unsigned short* orow = ctx + (size_t)(b * SEQ_ + qbase + l31) * 2048 + h * 64;
  #pragma unroll
  for (int dt = 0; dt < 2; ++dt) {
    #pragma unroll
    for (int rq = 0; rq < 4; ++rq) {
      const int r = rq * 4;
      const int d0 = dt * 32 + 8 * rq + 4 * half;
      float a0 = (dt ? acc1[r]     : acc0[r])     * linv;
      float a1 = (dt ? acc1[r + 1] : acc0[r + 1]) * linv;
      float a2 = (dt ? acc1[r + 2] : acc0[r + 2]) * linv;
      float a3 = (dt ? acc1[r + 3] : acc0[r + 3]) * linv;
      u32x2 o;
      o[0] = pack_bf2(a0, a1);
      o[1] = pack_bf2(a2, a3);
      *(u32x2*)(orow + d0) = o;
    }
  }
}

extern "C" void kernel_launch(void* const* d_in, const int* in_sizes, int n_in,
                              void* d_out, int out_size, void* d_ws, size_t ws_size,
                              hipStream_t stream) {
  const float* x  = (const float*)d_in[0];
  const float* cs = (const float*)d_in[2];
  const float* sn = (const float*)d_in[3];
  const float* Wq = (const float*)d_in[4];
  const float* Wk = (const float*)d_in[5];
  const float* Wv = (const float*)d_in[6];
  const float* Wo = (const float*)d_in[7];
  const float* qs = (const float*)d_in[8];
  const float* ks = (const float*)d_in[9];
  float* out = (float*)d_out;

  unsigned short* xb  = (unsigned short*)d_ws;
  unsigned short* Wt  = xb  + (size_t)4096 * 2048;
  unsigned short* Wot = Wt  + (size_t)3072 * 2048;
  unsigned short* qkv = Wot + (size_t)2048 * 2048;
  unsigned short* vTb = qkv + (size_t)4096 * 3072;
  unsigned short* ctx = vTb + (size_t)16 * 64 * 2048;

  cvtx<<<4096, 256, 0, stream>>>(x, xb);
  wtrans<<<dim3(32, 32), 256, 0, stream>>>(Wq, Wt, 2048);
  wtrans<<<dim3(8, 32),  256, 0, stream>>>(Wk, Wt + (size_t)2048 * 2048, 512);
  wtrans<<<dim3(8, 32),  256, 0, stream>>>(Wv, Wt + (size_t)2560 * 2048, 512);
  wtrans<<<dim3(32, 32), 256, 0, stream>>>(Wo, Wot, 2048);
  gemm_bt<1><<<dim3(24, 32), 256, 0, stream>>>(xb, Wt, qkv, 3072);
  rmsrope<<<dim3(1024, 32), 256, 0, stream>>>(qkv, qs, cs, sn, 0, 0.18033688f);
  rmsrope<<<dim3(1024, 8),  256, 0, stream>>>(qkv, ks, cs, sn, 2048, 1.0f);
  vtrans<<<dim3(32, 16), 256, 0, stream>>>(qkv, vTb);
  attn_mfma4<<<4096, 64, 0, stream>>>(qkv, vTb, ctx);
  gemm_bt<0><<<dim3(16, 32), 256, 0, stream>>>(ctx, Wot, out, 2048);
}

// Round 8
// 291.946 us; speedup vs baseline: 1.0132x; 1.0132x over previous
//
#include <hip/hip_runtime.h>
#include <hip/hip_bf16.h>
#include <cstdint>
#include <cstddef>

#define EMB   2048
#define NH_   32
#define NG_   8
#define DH_   64
#define SEQ_  2048
#define BB_   2
#define MTOT  4096
#define LDQKV 3072

typedef __attribute__((ext_vector_type(8))) short s16x8;
typedef __attribute__((ext_vector_type(8))) unsigned short u16x8;
typedef __attribute__((ext_vector_type(4))) float f32x4;
typedef __attribute__((ext_vector_type(16))) float f32x16;
typedef __attribute__((ext_vector_type(4))) unsigned int u32x4;
typedef __attribute__((ext_vector_type(2))) unsigned int u32x2;
typedef __attribute__((ext_vector_type(2))) int i32x2;

__device__ __forceinline__ float bf2f(unsigned short u) {
  unsigned int x = (unsigned int)u << 16; return __uint_as_float(x);
}
__device__ __forceinline__ unsigned short f2bf(float f) {
  unsigned int x = __float_as_uint(f);
  x = x + 0x7FFFu + ((x >> 16) & 1u);          // RNE
  return (unsigned short)(x >> 16);
}
__device__ __forceinline__ float ninf() { return __int_as_float(0xff800000); }
__device__ __forceinline__ unsigned int pack_bf2(float a, float b) {
  unsigned int r;
  asm("v_cvt_pk_bf16_f32 %0, %1, %2" : "=v"(r) : "v"(a), "v"(b));
  return r;
}
// lane i (<32): a.lo stays, a.hi <- b.lo ; b.lo <- a.hi, b.hi stays (32-lane half swap)
__device__ __forceinline__ void plswap(unsigned int& a, unsigned int& b) {
  i32x2 r = __builtin_amdgcn_permlane32_swap((int)a, (int)b, false, false);
  a = (unsigned int)r[0]; b = (unsigned int)r[1];
}
__device__ __forceinline__ void plswapf(float& a, float& b) {
  unsigned int ua = __float_as_uint(a), ub = __float_as_uint(b);
  plswap(ua, ub);
  a = __uint_as_float(ua); b = __uint_as_float(ub);
}

__device__ __forceinline__ void glds16(const void* g, void* l) {
  __builtin_amdgcn_global_load_lds((const __attribute__((address_space(1))) void*)g,
                                   (__attribute__((address_space(3))) void*)l, 16, 0, 0);
}

// ---------- x f32 -> bf16 ----------
__global__ __launch_bounds__(256)
void cvtx(const float* __restrict__ x, unsigned short* __restrict__ xb) {
  size_t i = (size_t)blockIdx.x * 256 + threadIdx.x;
  float4 a = *(const float4*)(x + i * 8);
  float4 c = *(const float4*)(x + i * 8 + 4);
  u16x8 o;
  o[0] = f2bf(a.x); o[1] = f2bf(a.y); o[2] = f2bf(a.z); o[3] = f2bf(a.w);
  o[4] = f2bf(c.x); o[5] = f2bf(c.y); o[6] = f2bf(c.z); o[7] = f2bf(c.w);
  *(u16x8*)(xb + i * 8) = o;
}

// ---------- W[K=2048][N] f32 -> Wt[N][2048] bf16 ----------
__global__ __launch_bounds__(256)
void wtrans(const float* __restrict__ in, unsigned short* __restrict__ out, int N) {
  __shared__ float tile[64][65];
  const int tid = threadIdx.x;
  const int n0 = blockIdx.x * 64, k0 = blockIdx.y * 64;
  #pragma unroll
  for (int jj = 0; jj < 4; ++jj) {
    int r = (tid >> 4) + jj * 16;
    int c = (tid & 15) * 4;
    float4 v = *(const float4*)(in + (size_t)(k0 + r) * N + n0 + c);
    tile[r][c] = v.x; tile[r][c + 1] = v.y; tile[r][c + 2] = v.z; tile[r][c + 3] = v.w;
  }
  __syncthreads();
  #pragma unroll
  for (int rep = 0; rep < 2; ++rep) {
    int u = rep * 256 + tid;
    int nl = u >> 3, ch = u & 7;
    u16x8 o;
    #pragma unroll
    for (int e = 0; e < 8; ++e) o[e] = f2bf(tile[ch * 8 + e][nl]);
    *(u16x8*)(out + (size_t)(n0 + nl) * 2048 + k0 + ch * 8) = o;
  }
}

// ---------- MFMA GEMM: C[M,N] = A[M,2048] @ Bt[N,2048]^T ; BM=BN=128, BK=32 ----------
template<int BF16OUT>
__global__ __launch_bounds__(256)
void gemm_bt(const unsigned short* __restrict__ A, const unsigned short* __restrict__ Bt,
             void* __restrict__ C, int ldc) {
  __shared__ __align__(16) unsigned short As[128 * 32];
  __shared__ __align__(16) unsigned short Bs[128 * 32];
  const int tid = threadIdx.x;
  const int w = tid >> 6, lane = tid & 63;
  const int grp = lane >> 4, l15 = lane & 15;
  const int wr = w >> 1, wc = w & 1;
  const int bm = blockIdx.y * 128, bn = blockIdx.x * 128;
  f32x4 acc[4][4] = {};
  for (int k0 = 0; k0 < 2048; k0 += 32) {
    #pragma unroll
    for (int j = 0; j < 2; ++j) {
      int unit = (j * 4 + w) * 64 + lane;
      int row = unit >> 2, ch = unit & 3;
      glds16(A  + (size_t)(bm + row) * 2048 + k0 + ch * 8, (char*)As + (j * 4 + w) * 1024);
      glds16(Bt + (size_t)(bn + row) * 2048 + k0 + ch * 8, (char*)Bs + (j * 4 + w) * 1024);
    }
    __syncthreads();
    s16x8 af[4], bf[4];
    #pragma unroll
    for (int i = 0; i < 4; ++i)
      af[i] = *(const s16x8*)((const char*)As + (wr * 64 + i * 16 + l15) * 64 + grp * 16);
    #pragma unroll
    for (int j = 0; j < 4; ++j)
      bf[j] = *(const s16x8*)((const char*)Bs + (wc * 64 + j * 16 + l15) * 64 + grp * 16);
    #pragma unroll
    for (int i = 0; i < 4; ++i)
      #pragma unroll
      for (int j = 0; j < 4; ++j)
        acc[i][j] = __builtin_amdgcn_mfma_f32_16x16x32_bf16(af[i], bf[j], acc[i][j], 0, 0, 0);
    __syncthreads();
  }
  #pragma unroll
  for (int i = 0; i < 4; ++i)
    #pragma unroll
    for (int j = 0; j < 4; ++j)
      #pragma unroll
      for (int r = 0; r < 4; ++r) {
        int row = bm + wr * 64 + i * 16 + grp * 4 + r;
        int col = bn + wc * 64 + j * 16 + l15;
        float v = acc[i][j][r];
        if (BF16OUT) ((unsigned short*)C)[(size_t)row * ldc + col] = f2bf(v);
        else         ((float*)C)[(size_t)row * ldc + col] = v;
      }
}

// ---------- fused RMSNorm(D=64) + RoPE, in-place bf16; optional post-scale ----------
__global__ __launch_bounds__(256)
void rmsrope(unsigned short* __restrict__ t, const float* __restrict__ scale,
             const float* __restrict__ cs, const float* __restrict__ sn, int coff, float post) {
  int m = blockIdx.x * 4 + (threadIdx.x >> 6);
  int h = blockIdx.y;
  int lane = threadIdx.x & 63;
  int spos = m & (SEQ_ - 1);
  unsigned short* p = t + (size_t)m * LDQKV + coff + h * 64 + lane;
  float val = bf2f(*p);
  float sq = val * val;
  #pragma unroll
  for (int off = 32; off; off >>= 1) sq += __shfl_xor(sq, off);
  float r = rsqrtf(sq * (1.f / 64.f) + 1e-6f);
  float xn = val * r * scale[lane];
  float partner = __shfl_xor(xn, 32);
  float c = cs[spos * 64 + lane], s = sn[spos * 64 + lane];
  float o = (lane < 32) ? (xn * c - partner * s) : fmaf(xn, c, partner * s);
  *p = f2bf(o * post);
}

// ---------- v region of qkv -> vT[(b*8+g)*64 + d][s] bf16 ----------
__global__ __launch_bounds__(256)
void vtrans(const unsigned short* __restrict__ qkv, unsigned short* __restrict__ vT) {
  __shared__ unsigned short tile[64][72];
  const int tid = threadIdx.x;
  const int st = blockIdx.x;
  const int bg = blockIdx.y;
  const int b = bg >> 3, g = bg & 7;
  #pragma unroll
  for (int rep = 0; rep < 2; ++rep) {
    int u = rep * 256 + tid;
    int sl = u >> 3, ch = u & 7;
    u16x8 v = *(const u16x8*)(qkv + (size_t)(b * SEQ_ + st * 64 + sl) * LDQKV + 2560 + g * 64 + ch * 8);
    #pragma unroll
    for (int e = 0; e < 8; ++e) tile[sl][ch * 8 + e] = v[e];
  }
  __syncthreads();
  #pragma unroll
  for (int rep = 0; rep < 2; ++rep) {
    int u = rep * 256 + tid;
    int d = u >> 3, ch = u & 7;
    u16x8 o;
    #pragma unroll
    for (int e = 0; e < 8; ++e) o[e] = tile[ch * 8 + e][d];
    *(u16x8*)(vT + (size_t)(bg * 64 + d) * SEQ_ + st * 64 + ch * 8) = o;
  }
}

// ---------- MFMA flash attention v5: no-max softmax, 4 independent waves/block ----------
// Same per-wave body as v4 (exact fixed-shift softmax: RMSNorm bounds |logit|),
// but packed 4 waves per 256-thread workgroup to escape the wg/CU occupancy cap.
// All 4 waves of a block share the same qt (uniform length -> block retires
// together); blocks ordered longest-tile-first. No LDS, no barriers.
__global__ __launch_bounds__(256)
void attn_mfma5(const unsigned short* __restrict__ qkv, const unsigned short* __restrict__ vT,
                unsigned short* __restrict__ ctx) {
  const int tid = threadIdx.x;
  const int w = tid >> 6, lane = tid & 63;
  const int l31 = lane & 31, half = lane >> 5;
  const int bid = blockIdx.x;                   // 0..1023
  const int qt = 63 - (bid >> 4);               // longest first, uniform per block
  const int bh = (bid & 15) * 4 + w;            // 0..63
  const int b = bh >> 5, h = bh & 31, g = h >> 2;
  const int qbase = qt * 32;
  const int nkt = qt + 1;

  const unsigned short* qp = qkv + (size_t)(b * SEQ_ + l31) * LDQKV + h * 64 + half * 8;
  const unsigned short* kp = qkv + (size_t)(b * SEQ_ + l31) * LDQKV + 2048 + g * 64 + half * 8;
  const unsigned short* vp = vT + (size_t)((b * NG_ + g) * 64 + l31) * SEQ_ + half * 8;

  s16x8 qf[4];
  #pragma unroll
  for (int s = 0; s < 4; ++s)
    qf[s] = *(const s16x8*)(qp + (size_t)qbase * LDQKV + s * 16);

  f32x16 acc0 = {}, acc1 = {};
  float l_st = 0.f;

  auto loadk = [&](s16x8 (&KF)[4], int kb) {
    #pragma unroll
    for (int s = 0; s < 4; ++s)
      KF[s] = *(const s16x8*)(kp + (size_t)kb * LDQKV + s * 16);
  };

  auto body = [&](const s16x8 (&KF)[4], int kt_) {
    const int kbase = kt_ * 32;
    s16x8 vf00 = *(const s16x8*)(vp + kbase);
    s16x8 vf01 = *(const s16x8*)(vp + kbase + 16);
    s16x8 vf10 = *(const s16x8*)(vp + (size_t)32 * SEQ_ + kbase);
    s16x8 vf11 = *(const s16x8*)(vp + (size_t)32 * SEQ_ + kbase + 16);
    f32x16 st = {};
    #pragma unroll
    for (int s = 0; s < 4; ++s)
      st = __builtin_amdgcn_mfma_f32_32x32x16_bf16(KF[s], qf[s], st, 0, 0, 0);
    if (kt_ == qt) {                           // mask key > q (kbase == qbase)
      #pragma unroll
      for (int r = 0; r < 16; ++r) {
        int key = (r & 3) + 8 * (r >> 2) + 4 * half;
        if (key > l31) st[r] = ninf();
      }
    }
    float p[16];
    #pragma unroll
    for (int r = 0; r < 16; ++r) p[r] = exp2f(st[r]);   // exp2(-inf)=0 handles mask
    float s8[8];
    #pragma unroll
    for (int r = 0; r < 8; ++r) s8[r] = p[r] + p[r + 8];
    float s4a = s8[0] + s8[1], s4b = s8[2] + s8[3];
    float s4c = s8[4] + s8[5], s4d = s8[6] + s8[7];
    float psum = (s4a + s4b) + (s4c + s4d);
    { float a = psum, bsw = psum; plswapf(a, bsw); psum = a + bsw; }
    l_st += psum;
    unsigned int PK[8];
    #pragma unroll
    for (int j = 0; j < 8; ++j) PK[j] = pack_bf2(p[2 * j], p[2 * j + 1]);
    plswap(PK[0], PK[2]); plswap(PK[1], PK[3]);
    plswap(PK[4], PK[6]); plswap(PK[5], PK[7]);
    u32x4 pb0u, pb1u;
    pb0u[0] = PK[0]; pb0u[1] = PK[1]; pb0u[2] = PK[2]; pb0u[3] = PK[3];
    pb1u[0] = PK[4]; pb1u[1] = PK[5]; pb1u[2] = PK[6]; pb1u[3] = PK[7];
    s16x8 pb0 = __builtin_bit_cast(s16x8, pb0u);
    s16x8 pb1 = __builtin_bit_cast(s16x8, pb1u);
    acc0 = __builtin_amdgcn_mfma_f32_32x32x16_bf16(vf00, pb0, acc0, 0, 0, 0);
    acc0 = __builtin_amdgcn_mfma_f32_32x32x16_bf16(vf01, pb1, acc0, 0, 0, 0);
    acc1 = __builtin_amdgcn_mfma_f32_32x32x16_bf16(vf10, pb0, acc1, 0, 0, 0);
    acc1 = __builtin_amdgcn_mfma_f32_32x32x16_bf16(vf11, pb1, acc1, 0, 0, 0);
  };

  s16x8 kA[4], kB[4];
  loadk(kA, 0);
  for (int kt = 0; kt < nkt; kt += 2) {
    loadk(kB, (kt + 1 < nkt) ? (kt + 1) * 32 : kt * 32);
    body(kA, kt);
    if (kt + 1 >= nkt) break;
    loadk(kA, (kt + 2 < nkt) ? (kt + 2) * 32 : (kt + 1) * 32);
    body(kB, kt + 1);
  }

  const float linv = 1.f / l_st;
  unsigned short* orow = ctx + (size_t)(b * SEQ_ + qbase + l31) * 2048 + h * 64;
  #pragma unroll
  for (int dt = 0; dt < 2; ++dt) {
    #pragma unroll
    for (int rq = 0; rq < 4; ++rq) {
      const int r = rq * 4;
      const int d0 = dt * 32 + 8 * rq + 4 * half;
      float a0 = (dt ? acc1[r]     : acc0[r])     * linv;
      float a1 = (dt ? acc1[r + 1] : acc0[r + 1]) * linv;
      float a2 = (dt ? acc1[r + 2] : acc0[r + 2]) * linv;
      float a3 = (dt ? acc1[r + 3] : acc0[r + 3]) * linv;
      u32x2 o;
      o[0] = pack_bf2(a0, a1);
      o[1] = pack_bf2(a2, a3);
      *(u32x2*)(orow + d0) = o;
    }
  }
}

extern "C" void kernel_launch(void* const* d_in, const int* in_sizes, int n_in,
                              void* d_out, int out_size, void* d_ws, size_t ws_size,
                              hipStream_t stream) {
  const float* x  = (const float*)d_in[0];
  const float* cs = (const float*)d_in[2];
  const float* sn = (const float*)d_in[3];
  const float* Wq = (const float*)d_in[4];
  const float* Wk = (const float*)d_in[5];
  const float* Wv = (const float*)d_in[6];
  const float* Wo = (const float*)d_in[7];
  const float* qs = (const float*)d_in[8];
  const float* ks = (const float*)d_in[9];
  float* out = (float*)d_out;

  unsigned short* xb  = (unsigned short*)d_ws;
  unsigned short* Wt  = xb  + (size_t)4096 * 2048;
  unsigned short* Wot = Wt  + (size_t)3072 * 2048;
  unsigned short* qkv = Wot + (size_t)2048 * 2048;
  unsigned short* vTb = qkv + (size_t)4096 * 3072;
  unsigned short* ctx = vTb + (size_t)16 * 64 * 2048;

  cvtx<<<4096, 256, 0, stream>>>(x, xb);
  wtrans<<<dim3(32, 32), 256, 0, stream>>>(Wq, Wt, 2048);
  wtrans<<<dim3(8, 32),  256, 0, stream>>>(Wk, Wt + (size_t)2048 * 2048, 512);
  wtrans<<<dim3(8, 32),  256, 0, stream>>>(Wv, Wt + (size_t)2560 * 2048, 512);
  wtrans<<<dim3(32, 32), 256, 0, stream>>>(Wo, Wot, 2048);
  gemm_bt<1><<<dim3(24, 32), 256, 0, stream>>>(xb, Wt, qkv, 3072);
  rmsrope<<<dim3(1024, 32), 256, 0, stream>>>(qkv, qs, cs, sn, 0, 0.18033688f);
  rmsrope<<<dim3(1024, 8),  256, 0, stream>>>(qkv, ks, cs, sn, 2048, 1.0f);
  vtrans<<<dim3(32, 16), 256, 0, stream>>>(qkv, vTb);
  attn_mfma5<<<1024, 256, 0, stream>>>(qkv, vTb, ctx);
  gemm_bt<0><<<dim3(16, 32), 256, 0, stream>>>(ctx, Wot, out, 2048);
}